// Round 1
// baseline (462.848 us; speedup 1.0000x reference)
//
#include <hip/hip_runtime.h>

#define MAXV 10000.0f

// x: (BC, H, W) fp32, 3x3 structuring element. One thread computes one float4
// of output (4 contiguous pixels in W). Geodesic border: out-of-range taps
// read as +MAXV. Bias: active taps (kernel!=0) subtract 0, inactive subtract
// -MAXV — matching the reference's fp32 arithmetic exactly.
__global__ __launch_bounds__(256)
void erode3x3_kernel(const float* __restrict__ x,
                     const float* __restrict__ kern,
                     float* __restrict__ out,
                     int H, int W, int segs /* = W/4 */) {
    long long idx = (long long)blockIdx.x * blockDim.x + threadIdx.x;
    int seg = (int)(idx % segs);
    int y   = (int)((idx / segs) % H);
    long long bc = idx / ((long long)segs * (long long)H);

    // neighborhood bias (wave-uniform; 9 broadcast loads)
    float nv[3][3];
#pragma unroll
    for (int i = 0; i < 3; ++i)
#pragma unroll
        for (int j = 0; j < 3; ++j)
            nv[i][j] = (kern[i * 3 + j] == 0.0f) ? -MAXV : 0.0f;

    const float* base = x + bc * (long long)H * (long long)W;
    const int x0 = seg * 4;

    float res0 = 3.4e38f, res1 = 3.4e38f, res2 = 3.4e38f, res3 = 3.4e38f;

#pragma unroll
    for (int i = 0; i < 3; ++i) {
        const int ry = y + i - 1;
        float v0, v1, v2, v3, v4, v5;  // [x0-1 .. x0+4]
        if (ry >= 0 && ry < H) {
            const float* rp = base + (long long)ry * W + x0;
            const float4 b = *(const float4*)rp;
            v0 = (seg > 0)        ? rp[-1] : MAXV;
            v1 = b.x; v2 = b.y; v3 = b.z; v4 = b.w;
            v5 = (seg < segs - 1) ? rp[4]  : MAXV;
        } else {
            v0 = v1 = v2 = v3 = v4 = v5 = MAXV;
        }
        const float n0 = nv[i][0], n1 = nv[i][1], n2 = nv[i][2];
        res0 = fminf(res0, fminf(fminf(v0 - n0, v1 - n1), v2 - n2));
        res1 = fminf(res1, fminf(fminf(v1 - n0, v2 - n1), v3 - n2));
        res2 = fminf(res2, fminf(fminf(v2 - n0, v3 - n1), v4 - n2));
        res3 = fminf(res3, fminf(fminf(v3 - n0, v4 - n1), v5 - n2));
    }

    float4 o;
    o.x = res0; o.y = res1; o.z = res2; o.w = res3;
    *(float4*)(out + bc * (long long)H * W + (long long)y * W + x0) = o;
}

extern "C" void kernel_launch(void* const* d_in, const int* in_sizes, int n_in,
                              void* d_out, int out_size, void* d_ws, size_t ws_size,
                              hipStream_t stream) {
    const float* x    = (const float*)d_in[0];
    const float* kern = (const float*)d_in[1];
    float* out        = (float*)d_out;

    const int H = 1024, W = 1024;
    const int segs = W / 4;                       // 256 float4-segments per row
    const long long total = (long long)out_size / 4;  // threads = elements/4
    const int block = 256;
    const long long grid = (total + block - 1) / block;

    erode3x3_kernel<<<(dim3)(unsigned)grid, block, 0, stream>>>(
        x, kern, out, H, W, segs);
}

// Round 2
// 438.963 us; speedup vs baseline: 1.0544x; 1.0544x over previous
//
#include <hip/hip_runtime.h>

#define MAXV 10000.0f

__device__ __forceinline__ float min3f(float a, float b, float c) {
    return fminf(fminf(a, b), c);
}

// 3x3 erosion, fp32. Each thread: 4-wide x R-tall column strip.
// Loads R+2 input rows once; rolling 3-row window in registers.
// Fast path (all 9 taps active, the common case): separable min3 H then V.
// Slow path (general structuring element): exact 9-tap with biases,
// matching the reference's fp32 arithmetic (v - neigh[i][j]).
template <int R>
__global__ __launch_bounds__(256)
void erode3x3_rows(const float* __restrict__ x,
                   const float* __restrict__ kern,
                   float* __restrict__ out,
                   int H, int W, int segs, int ytiles) {
    long long gid = (long long)blockIdx.x * blockDim.x + threadIdx.x;
    int seg   = (int)(gid % segs);
    int ytile = (int)((gid / segs) % ytiles);
    long long bc = gid / ((long long)segs * ytiles);

    // structuring element (wave-uniform broadcast loads)
    float nv[3][3];
    bool all_active = true;
#pragma unroll
    for (int i = 0; i < 3; ++i)
#pragma unroll
        for (int j = 0; j < 3; ++j) {
            float kv = kern[i * 3 + j];
            nv[i][j] = (kv == 0.0f) ? -MAXV : 0.0f;
            all_active = all_active && (kv != 0.0f);
        }

    const int y0 = ytile * R;
    const int x0 = seg * 4;
    const float* base  = x   + bc * (long long)H * W;
    float*       obase = out + bc * (long long)H * W;

    if (all_active) {
        // separable: h = horizontal min3, out = vertical min3 of h
        float4 ha, hb, hc;
        ha.x = ha.y = ha.z = ha.w = MAXV;
        hb = ha; hc = ha;
#pragma unroll
        for (int r = 0; r < R + 2; ++r) {
            const int ry = y0 - 1 + r;
            float4 h;
            if (ry >= 0 && ry < H) {
                const float* rp = base + (long long)ry * W + x0;
                const float4 b = *(const float4*)rp;
                const float v0 = (seg > 0)        ? rp[-1] : MAXV;
                const float v5 = (seg < segs - 1) ? rp[4]  : MAXV;
                h.x = min3f(v0,  b.x, b.y);
                h.y = min3f(b.x, b.y, b.z);
                h.z = min3f(b.y, b.z, b.w);
                h.w = min3f(b.z, b.w, v5);
            } else {
                h.x = h.y = h.z = h.w = MAXV;
            }
            ha = hb; hb = hc; hc = h;
            if (r >= 2) {
                float4 o;
                o.x = min3f(ha.x, hb.x, hc.x);
                o.y = min3f(ha.y, hb.y, hc.y);
                o.z = min3f(ha.z, hb.z, hc.z);
                o.w = min3f(ha.w, hb.w, hc.w);
                *(float4*)(obase + (long long)(ry - 1) * W + x0) = o;
            }
        }
    } else {
        // generic: keep raw 6-wide rows, exact 9-tap with biases
        float a0[6], a1[6], a2[6];
#pragma unroll
        for (int j = 0; j < 6; ++j) { a0[j] = a1[j] = a2[j] = MAXV; }
#pragma unroll
        for (int r = 0; r < R + 2; ++r) {
            const int ry = y0 - 1 + r;
            float cur[6];
            if (ry >= 0 && ry < H) {
                const float* rp = base + (long long)ry * W + x0;
                const float4 b = *(const float4*)rp;
                cur[0] = (seg > 0)        ? rp[-1] : MAXV;
                cur[1] = b.x; cur[2] = b.y; cur[3] = b.z; cur[4] = b.w;
                cur[5] = (seg < segs - 1) ? rp[4]  : MAXV;
            } else {
#pragma unroll
                for (int j = 0; j < 6; ++j) cur[j] = MAXV;
            }
#pragma unroll
            for (int j = 0; j < 6; ++j) { a0[j] = a1[j]; a1[j] = a2[j]; a2[j] = cur[j]; }
            if (r >= 2) {
                float o[4];
#pragma unroll
                for (int e = 0; e < 4; ++e) {
                    float m = 3.4e38f;
#pragma unroll
                    for (int j = 0; j < 3; ++j) {
                        m = fminf(m, a0[e + j] - nv[0][j]);
                        m = fminf(m, a1[e + j] - nv[1][j]);
                        m = fminf(m, a2[e + j] - nv[2][j]);
                    }
                    o[e] = m;
                }
                float4 ov; ov.x = o[0]; ov.y = o[1]; ov.z = o[2]; ov.w = o[3];
                *(float4*)(obase + (long long)(ry - 1) * W + x0) = ov;
            }
        }
    }
}

extern "C" void kernel_launch(void* const* d_in, const int* in_sizes, int n_in,
                              void* d_out, int out_size, void* d_ws, size_t ws_size,
                              hipStream_t stream) {
    const float* x    = (const float*)d_in[0];
    const float* kern = (const float*)d_in[1];
    float* out        = (float*)d_out;

    const int H = 1024, W = 1024;
    constexpr int R = 16;                 // output rows per thread
    const int segs   = W / 4;             // 256 float4-segments per row
    const int ytiles = H / R;             // 64
    const long long BC = (long long)out_size / ((long long)H * W);  // 64

    const long long total = BC * (long long)ytiles * segs;  // threads
    const int block = 256;
    const long long grid = (total + block - 1) / block;

    erode3x3_rows<R><<<(dim3)(unsigned)grid, block, 0, stream>>>(
        x, kern, out, H, W, segs, ytiles);
}